// Round 5
// baseline (112.681 us; speedup 1.0000x reference)
//
#include <hip/hip_runtime.h>
#include <math.h>

#define BATCH 16
#define SEQ   4096
#define HDIM  1024
#define DV    2048          // 2*H
#define NCH2  128           // s-chunks in fused kernel
#define SCH2  (SEQ / NCH2)  // 32 rows per chunk

typedef float vf4 __attribute__((ext_vector_type(4)));

__device__ __forceinline__ float tanh_fast(float x) {
    // tanh(x) = 1 - 2/(1+exp(2x)); robust at +/-inf
    float e = __expf(2.0f * x);
    return 1.0f - 2.0f * __builtin_amdgcn_rcpf(1.0f + e);
}

__device__ __forceinline__ float4 ntload4(const float4* p) {
    vf4 v = __builtin_nontemporal_load((const vf4*)p);
    return make_float4(v.x, v.y, v.z, v.w);
}

// K1: q[b,o] = sum_h query[b,h] * Wq[o,h]   (wave per o, loop over b)
__global__ __launch_bounds__(256) void k1_q(const float* __restrict__ query,
                                            const float* __restrict__ Wq,
                                            float* __restrict__ qout) {
    int wave = threadIdx.x >> 6;
    int lane = threadIdx.x & 63;
    int o = blockIdx.x * 4 + wave;
    const float4* wq4 = (const float4*)(Wq + (size_t)o * HDIM);
    float4 w[4];
#pragma unroll
    for (int k = 0; k < 4; ++k) w[k] = wq4[k * 64 + lane];
#pragma unroll
    for (int b = 0; b < BATCH; ++b) {
        const float4* q4 = (const float4*)(query + b * HDIM);
        float acc = 0.f;
#pragma unroll
        for (int k = 0; k < 4; ++k) {
            float4 q = q4[k * 64 + lane];
            acc += w[k].x * q.x + w[k].y * q.y + w[k].z * q.z + w[k].w * q.w;
        }
#pragma unroll
        for (int off = 32; off; off >>= 1) acc += __shfl_down(acc, off, 64);
        if (lane == 0) qout[b * HDIM + o] = acc;
    }
}

// KF: fused scores + chunk-local exp + context partials, with mask compaction.
// Grid: B*NCH2 = 2048 blocks (bid = b*NCH2 + c), 256 threads (4 waves).
__global__ __launch_bounds__(256) void kf_fused(const float* __restrict__ pk,
                                                const float* __restrict__ qv,
                                                const float* __restrict__ we,
                                                const int* __restrict__ mask,
                                                const float* __restrict__ value,
                                                float* __restrict__ scores,
                                                float* __restrict__ partial) {
    int bid = blockIdx.x;
    int b = bid >> 7;                 // NCH2 = 128
    int c = bid & (NCH2 - 1);
    int s0 = c * SCH2;
    int t = threadIdx.x;
    int wave = t >> 6;
    int lane = t & 63;

    __shared__ float s_sc[SCH2];
    __shared__ float s_a[SCH2];
    __shared__ int   s_list[SCH2];
    __shared__ int   s_nact;

    // ---- compaction: lanes 0..31 of wave 0 read the chunk's 32 masks ----
    if (t < SCH2) {
        int r = b * SEQ + s0 + t;
        int pred = (mask[r] != 0);
        unsigned long long bal = __ballot(pred);
        if (pred) {
            int pos = __popcll(bal & ((1ull << lane) - 1ull));
            s_list[pos] = t;
        } else {
            s_sc[t] = -INFINITY;
            scores[r] = -INFINITY;
        }
        if (lane == 0) s_nact = __popcll(bal);
    }

    const float4* q4  = (const float4*)(qv + b * HDIM);
    const float4* we4 = (const float4*)we;
    float4 qr[4], wr[4];
#pragma unroll
    for (int k = 0; k < 4; ++k) {
        qr[k] = q4[k * 64 + lane];
        wr[k] = we4[k * 64 + lane];
    }
    __syncthreads();
    int nact = s_nact;

    // ---- phase 1: scores for active rows only (wave-strided, balanced) ----
    for (int j = wave; j < nact; j += 4) {
        int s = s_list[j];
        int r = b * SEQ + s0 + s;
        const float4* row = (const float4*)(pk + (size_t)r * HDIM);
        float acc = 0.f;
#pragma unroll
        for (int k = 0; k < 4; ++k) {
            float4 p = ntload4(row + k * 64 + lane);
            acc += tanh_fast(p.x + qr[k].x) * wr[k].x;
            acc += tanh_fast(p.y + qr[k].y) * wr[k].y;
            acc += tanh_fast(p.z + qr[k].z) * wr[k].z;
            acc += tanh_fast(p.w + qr[k].w) * wr[k].w;
        }
#pragma unroll
        for (int off = 32; off; off >>= 1) acc += __shfl_down(acc, off, 64);
        if (lane == 0) {
            s_sc[s] = acc;
            scores[r] = acc;
        }
    }
    __syncthreads();

    // ---- chunk max + weights ----
    float mc = -INFINITY;
#pragma unroll
    for (int s = 0; s < SCH2; ++s) mc = fmaxf(mc, s_sc[s]);   // LDS broadcast
    if (t < SCH2)
        s_a[t] = (s_sc[t] == -INFINITY || mc == -INFINITY) ? 0.f : __expf(s_sc[t] - mc);
    __syncthreads();

    // ---- phase 2: weighted value accumulation over active rows, 2-row unroll ----
    const float4* v4 = (const float4*)(value + (size_t)b * SEQ * DV);
    float4 a0 = make_float4(0.f, 0.f, 0.f, 0.f);
    float4 a1 = make_float4(0.f, 0.f, 0.f, 0.f);
    float4 b0 = make_float4(0.f, 0.f, 0.f, 0.f);
    float4 b1 = make_float4(0.f, 0.f, 0.f, 0.f);
    int j = 0;
    for (; j + 1 < nact; j += 2) {
        int sA = s_list[j];
        int sB = s_list[j + 1];
        float aA = s_a[sA];
        float aB = s_a[sB];
        const float4* vrA = v4 + (size_t)(s0 + sA) * (DV / 4);
        const float4* vrB = v4 + (size_t)(s0 + sB) * (DV / 4);
        float4 uA = ntload4(vrA + t);
        float4 vA = ntload4(vrA + t + 256);
        float4 uB = ntload4(vrB + t);
        float4 vB = ntload4(vrB + t + 256);
        a0.x += aA * uA.x; a0.y += aA * uA.y; a0.z += aA * uA.z; a0.w += aA * uA.w;
        a1.x += aA * vA.x; a1.y += aA * vA.y; a1.z += aA * vA.z; a1.w += aA * vA.w;
        b0.x += aB * uB.x; b0.y += aB * uB.y; b0.z += aB * uB.z; b0.w += aB * uB.w;
        b1.x += aB * vB.x; b1.y += aB * vB.y; b1.z += aB * vB.z; b1.w += aB * vB.w;
    }
    if (j < nact) {
        int s = s_list[j];
        float a = s_a[s];
        const float4* vr = v4 + (size_t)(s0 + s) * (DV / 4);
        float4 u = ntload4(vr + t);
        float4 v = ntload4(vr + t + 256);
        a0.x += a * u.x; a0.y += a * u.y; a0.z += a * u.z; a0.w += a * u.w;
        a1.x += a * v.x; a1.y += a * v.y; a1.z += a * v.z; a1.w += a * v.w;
    }
    a0.x += b0.x; a0.y += b0.y; a0.z += b0.z; a0.w += b0.w;
    a1.x += b1.x; a1.y += b1.y; a1.z += b1.z; a1.w += b1.w;
    float4* pout = (float4*)(partial + (size_t)bid * DV);
    pout[t] = a0;
    pout[t + 256] = a1;
}

// KZ: finalize. Grid B*16 = 256 blocks (bid = b*16 + q), 256 threads.
// Each block: recompute m/Z from scores (L2-hot 16KB), write alphas rows
// [q*256, q*256+256) and ctx cols [q*128, q*128+128).
__global__ __launch_bounds__(256) void kz_final(const float* __restrict__ scores,
                                                const float* __restrict__ partial,
                                                float* __restrict__ ctx,
                                                float* __restrict__ alphas) {
    int bid = blockIdx.x;
    int b = bid >> 4;
    int q = bid & 15;
    int t = threadIdx.x;
    int wave = t >> 6;
    int lane = t & 63;

    __shared__ float s_raw[SEQ];
    __shared__ float s_g[NCH2];
    __shared__ float red[8];
    __shared__ float s_half[128];

    // load scores[b] into LDS (coalesced float4)
    const float4* sc4 = (const float4*)(scores + (size_t)b * SEQ);
    float4* raw4 = (float4*)s_raw;
#pragma unroll
    for (int i = 0; i < 4; ++i) raw4[t + i * 256] = sc4[t + i * 256];
    __syncthreads();

    // global max m
    float m = -INFINITY;
#pragma unroll
    for (int i = 0; i < 16; ++i) m = fmaxf(m, s_raw[t + i * 256]);
#pragma unroll
    for (int off = 32; off; off >>= 1) m = fmaxf(m, __shfl_down(m, off, 64));
    if (lane == 0) red[wave] = m;
    __syncthreads();
    m = fmaxf(fmaxf(red[0], red[1]), fmaxf(red[2], red[3]));

    // Z
    float z = 0.f;
#pragma unroll
    for (int i = 0; i < 16; ++i) {
        float v = s_raw[t + i * 256];
        z += (v == -INFINITY) ? 0.f : __expf(v - m);
    }
#pragma unroll
    for (int off = 32; off; off >>= 1) z += __shfl_down(z, off, 64);
    if (lane == 0) red[4 + wave] = z;
    __syncthreads();
    float Z = red[4] + red[5] + red[6] + red[7];
    float inv = 1.0f / Z;

    // per-chunk scale factors (rotated scan start -> fewer bank conflicts)
    if (t < NCH2) {
        float mcv = -INFINITY;
#pragma unroll
        for (int j = 0; j < SCH2; ++j)
            mcv = fmaxf(mcv, s_raw[t * SCH2 + ((j + t) & (SCH2 - 1))]);
        s_g[t] = (mcv == -INFINITY) ? 0.f : __expf(mcv - m);
    }

    // alphas rows [q*256, q*256+256)
    {
        float v = s_raw[q * 256 + t];
        float e = (v == -INFINITY) ? 0.f : __expf(v - m);
        alphas[(size_t)b * SEQ + q * 256 + t] = e * inv;
    }
    __syncthreads();

    // ctx cols [q*128, q*128+128): half 0 sums chunks 0..63, half 1 sums 64..127
    int col = q * 128 + (t & 127);
    int half = t >> 7;
    float sum = 0.f;
    const float* pbase = partial + (size_t)b * NCH2 * DV + col;
#pragma unroll 4
    for (int cc = half * 64; cc < half * 64 + 64; ++cc) {
        float g = s_g[cc];
        if (g != 0.f) sum += g * pbase[(size_t)cc * DV];
    }
    if (half == 1) s_half[t & 127] = sum;
    __syncthreads();
    if (half == 0)
        ctx[(size_t)b * DV + col] = (sum + s_half[t]) * inv;
}

// ---------- fallback path (tiny ws) ----------
__global__ __launch_bounds__(256) void k2_scores(const float* __restrict__ pk,
                                                 const float* __restrict__ qv,
                                                 const float* __restrict__ we,
                                                 const int* __restrict__ mask,
                                                 float* __restrict__ scores) {
    int wave = threadIdx.x >> 6;
    int lane = threadIdx.x & 63;
    int r = blockIdx.x * 4 + wave;
    int b = r >> 12;
    if (mask[r] == 0) { if (lane == 0) scores[r] = -INFINITY; return; }
    const float4* row = (const float4*)(pk + (size_t)r * HDIM);
    const float4* q4  = (const float4*)(qv + b * HDIM);
    const float4* we4 = (const float4*)we;
    float acc = 0.f;
#pragma unroll
    for (int k = 0; k < 4; ++k) {
        int idx = k * 64 + lane;
        float4 p = row[idx];
        float4 q = q4[idx];
        float4 w = we4[idx];
        acc += tanh_fast(p.x + q.x) * w.x;
        acc += tanh_fast(p.y + q.y) * w.y;
        acc += tanh_fast(p.z + q.z) * w.z;
        acc += tanh_fast(p.w + q.w) * w.w;
    }
#pragma unroll
    for (int off = 32; off; off >>= 1) acc += __shfl_down(acc, off, 64);
    if (lane == 0) scores[r] = acc;
}

__global__ __launch_bounds__(256) void k3_softmax(const float* __restrict__ scores,
                                                  float* __restrict__ alphas) {
    int b = blockIdx.x;
    int t = threadIdx.x;
    const float* sc = scores + b * SEQ;
    float loc[16];
    float m = -INFINITY;
#pragma unroll
    for (int i = 0; i < 16; ++i) { loc[i] = sc[t + i * 256]; m = fmaxf(m, loc[i]); }
#pragma unroll
    for (int off = 32; off; off >>= 1) m = fmaxf(m, __shfl_down(m, off, 64));
    __shared__ float redm[4];
    if ((t & 63) == 0) redm[t >> 6] = m;
    __syncthreads();
    m = fmaxf(fmaxf(redm[0], redm[1]), fmaxf(redm[2], redm[3]));
    float sum = 0.f;
#pragma unroll
    for (int i = 0; i < 16; ++i) {
        loc[i] = (loc[i] == -INFINITY) ? 0.f : __expf(loc[i] - m);
        sum += loc[i];
    }
#pragma unroll
    for (int off = 32; off; off >>= 1) sum += __shfl_down(sum, off, 64);
    __shared__ float reds[4];
    if ((t & 63) == 0) reds[t >> 6] = sum;
    __syncthreads();
    float inv = 1.0f / (reds[0] + reds[1] + reds[2] + reds[3]);
#pragma unroll
    for (int i = 0; i < 16; ++i) alphas[b * SEQ + t + i * 256] = loc[i] * inv;
}

__global__ __launch_bounds__(256) void k4_atomic(const float* __restrict__ value,
                                                 const float* __restrict__ alphas,
                                                 float* __restrict__ ctx) {
    int bid = blockIdx.x;
    int ch = bid & 31;
    int dt = (bid >> 5) & 1;
    int b  = bid >> 6;
    int t  = threadIdx.x;
    const float4* v4 = (const float4*)(value + (size_t)b * SEQ * DV + dt * 1024);
    const float* al = alphas + b * SEQ + ch * 128;
    float4 acc = make_float4(0.f, 0.f, 0.f, 0.f);
    for (int s = 0; s < 128; ++s) {
        float a = al[s];
        if (a != 0.f) {
            float4 v = v4[(size_t)(ch * 128 + s) * (DV / 4) + t];
            acc.x += a * v.x; acc.y += a * v.y; acc.z += a * v.z; acc.w += a * v.w;
        }
    }
    float* dst = ctx + (size_t)b * DV + dt * 1024 + t * 4;
    atomicAdd(dst + 0, acc.x);
    atomicAdd(dst + 1, acc.y);
    atomicAdd(dst + 2, acc.z);
    atomicAdd(dst + 3, acc.w);
}

extern "C" void kernel_launch(void* const* d_in, const int* in_sizes, int n_in,
                              void* d_out, int out_size, void* d_ws, size_t ws_size,
                              hipStream_t stream) {
    const float* query = (const float*)d_in[0];
    const float* pk    = (const float*)d_in[1];
    const float* value = (const float*)d_in[2];
    const float* Wq    = (const float*)d_in[3];
    const float* we    = (const float*)d_in[4];
    const int*   mask  = (const int*)d_in[5];

    float* out    = (float*)d_out;
    float* ctx    = out;                      // [B, 2H]
    float* alphas = out + BATCH * DV;         // [B, S]

    float* ws     = (float*)d_ws;
    float* qws    = ws;                                  // 16384 floats
    float* scores = ws + BATCH * HDIM;                   // 65536 floats
    float* partial = scores + BATCH * SEQ;               // B*NCH2*DV = 4M floats

    k1_q<<<HDIM / 4, 256, 0, stream>>>(query, Wq, qws);

    size_t need = (size_t)(BATCH * HDIM + BATCH * SEQ + (size_t)BATCH * NCH2 * DV) * sizeof(float);
    if (ws_size >= need) {
        kf_fused<<<BATCH * NCH2, 256, 0, stream>>>(pk, qws, we, mask, value, scores, partial);
        kz_final<<<BATCH * 16, 256, 0, stream>>>(scores, partial, ctx, alphas);
    } else {
        k2_scores<<<(BATCH * SEQ) / 4, 256, 0, stream>>>(pk, qws, we, mask, scores);
        k3_softmax<<<BATCH, 256, 0, stream>>>(scores, alphas);
        (void)hipMemsetAsync(ctx, 0, (size_t)BATCH * DV * sizeof(float), stream);
        k4_atomic<<<BATCH * 64, 256, 0, stream>>>(value, alphas, ctx);
    }
}

// Round 6
// 109.868 us; speedup vs baseline: 1.0256x; 1.0256x over previous
//
#include <hip/hip_runtime.h>
#include <math.h>

#define BATCH 16
#define SEQ   4096
#define HDIM  1024
#define DV    2048          // 2*H
#define NCH   32            // s-chunks in fused kernel
#define SCH   (SEQ / NCH)   // 128 rows per chunk

typedef float vf4 __attribute__((ext_vector_type(4)));

__device__ __forceinline__ float tanh_fast(float x) {
    // tanh(x) = 1 - 2/(1+exp(2x)); robust at +/-inf
    float e = __expf(2.0f * x);
    return 1.0f - 2.0f * __builtin_amdgcn_rcpf(1.0f + e);
}

__device__ __forceinline__ float4 ntload4(const float4* p) {
    vf4 v = __builtin_nontemporal_load((const vf4*)p);
    return make_float4(v.x, v.y, v.z, v.w);
}

// K1: q[b,o] = sum_h query[b,h] * Wq[o,h]   (wave per o, loop over b)
__global__ __launch_bounds__(256) void k1_q(const float* __restrict__ query,
                                            const float* __restrict__ Wq,
                                            float* __restrict__ qout) {
    int wave = threadIdx.x >> 6;
    int lane = threadIdx.x & 63;
    int o = blockIdx.x * 4 + wave;
    const float4* wq4 = (const float4*)(Wq + (size_t)o * HDIM);
    float4 w[4];
#pragma unroll
    for (int k = 0; k < 4; ++k) w[k] = wq4[k * 64 + lane];
#pragma unroll
    for (int b = 0; b < BATCH; ++b) {
        const float4* q4 = (const float4*)(query + b * HDIM);
        float acc = 0.f;
#pragma unroll
        for (int k = 0; k < 4; ++k) {
            float4 q = q4[k * 64 + lane];
            acc += w[k].x * q.x + w[k].y * q.y + w[k].z * q.z + w[k].w * q.w;
        }
#pragma unroll
        for (int off = 32; off; off >>= 1) acc += __shfl_down(acc, off, 64);
        if (lane == 0) qout[b * HDIM + o] = acc;
    }
}

// KF: fused scores + chunk-local exp + context partials + chunk stats.
// Grid: B*NCH = 512 blocks (bid = b*NCH + c), 256 threads (4 waves).
__global__ __launch_bounds__(256) void kf_fused(const float* __restrict__ pk,
                                                const float* __restrict__ qv,
                                                const float* __restrict__ we,
                                                const int* __restrict__ mask,
                                                const float* __restrict__ value,
                                                float* __restrict__ scores,
                                                float* __restrict__ partial,
                                                float* __restrict__ chunkm,
                                                float* __restrict__ chunkz) {
    int bid = blockIdx.x;
    int b = bid >> 5;                 // NCH = 32
    int c = bid & (NCH - 1);
    int s0 = c * SCH;
    int t = threadIdx.x;
    int wave = t >> 6;
    int lane = t & 63;

    __shared__ float s_sc[SCH];
    __shared__ float s_a[SCH];
    __shared__ int   s_list[SCH];
    __shared__ int   s_nact;
    __shared__ float red[8];

    // ---- compaction: wave 0 ballots rows in two 64-row halves ----
    if (t < 64) {
        int r0 = b * SEQ + s0 + t;
        int p0 = (mask[r0] != 0);
        unsigned long long b0 = __ballot(p0);
        int n0 = __popcll(b0);
        if (p0) {
            s_list[__popcll(b0 & ((1ull << lane) - 1ull))] = t;
        } else {
            s_sc[t] = -INFINITY;
            scores[r0] = -INFINITY;
        }
        int r1 = b * SEQ + s0 + 64 + t;
        int p1 = (mask[r1] != 0);
        unsigned long long b1 = __ballot(p1);
        if (p1) {
            s_list[n0 + __popcll(b1 & ((1ull << lane) - 1ull))] = 64 + t;
        } else {
            s_sc[64 + t] = -INFINITY;
            scores[r1] = -INFINITY;
        }
        if (lane == 0) s_nact = n0 + __popcll(b1);
    }

    const float4* q4  = (const float4*)(qv + b * HDIM);
    const float4* we4 = (const float4*)we;
    float4 qr[4], wr[4];
#pragma unroll
    for (int k = 0; k < 4; ++k) {
        qr[k] = q4[k * 64 + lane];
        wr[k] = we4[k * 64 + lane];
    }
    __syncthreads();
    int nact = s_nact;

    // ---- phase 1: scores for active rows only (wave-strided, balanced) ----
    for (int j = wave; j < nact; j += 4) {
        int s = s_list[j];
        int r = b * SEQ + s0 + s;
        const float4* row = (const float4*)(pk + (size_t)r * HDIM);
        float acc = 0.f;
#pragma unroll
        for (int k = 0; k < 4; ++k) {
            float4 p = ntload4(row + k * 64 + lane);
            acc += tanh_fast(p.x + qr[k].x) * wr[k].x;
            acc += tanh_fast(p.y + qr[k].y) * wr[k].y;
            acc += tanh_fast(p.z + qr[k].z) * wr[k].z;
            acc += tanh_fast(p.w + qr[k].w) * wr[k].w;
        }
#pragma unroll
        for (int off = 32; off; off >>= 1) acc += __shfl_down(acc, off, 64);
        if (lane == 0) {
            s_sc[s] = acc;
            scores[r] = acc;
        }
    }
    __syncthreads();

    // ---- chunk max (parallel reduce over 128 values via 2 waves) ----
    float mval = (t < SCH) ? s_sc[t] : -INFINITY;
    float mr = mval;
#pragma unroll
    for (int off = 32; off; off >>= 1) mr = fmaxf(mr, __shfl_down(mr, off, 64));
    if (lane == 0) red[wave] = mr;
    __syncthreads();
    float mc = fmaxf(fmaxf(red[0], red[1]), fmaxf(red[2], red[3]));

    // weights a_s = exp(sc - m_c); z_c = sum a_s
    float av = 0.f;
    if (t < SCH) {
        av = (mval == -INFINITY || mc == -INFINITY) ? 0.f : __expf(mval - mc);
        s_a[t] = av;
    }
    float zr = av;
#pragma unroll
    for (int off = 32; off; off >>= 1) zr += __shfl_down(zr, off, 64);
    if (lane == 0) red[4 + wave] = zr;
    __syncthreads();
    if (t == 0) {
        chunkm[bid] = mc;
        chunkz[bid] = red[4] + red[5];   // waves 0,1 cover t<128
    }

    // ---- phase 2: weighted value accumulation over active rows ----
    const float4* v4 = (const float4*)(value + (size_t)b * SEQ * DV);
    float4 a0 = make_float4(0.f, 0.f, 0.f, 0.f);
    float4 a1 = make_float4(0.f, 0.f, 0.f, 0.f);
    for (int j = 0; j < nact; ++j) {
        int s = s_list[j];
        float a = s_a[s];
        const float4* vr = v4 + (size_t)(s0 + s) * (DV / 4);
        float4 u = ntload4(vr + t);
        float4 v = ntload4(vr + t + 256);
        a0.x += a * u.x; a0.y += a * u.y; a0.z += a * u.z; a0.w += a * u.w;
        a1.x += a * v.x; a1.y += a * v.y; a1.z += a * v.z; a1.w += a * v.w;
    }
    float4* pout = (float4*)(partial + (size_t)bid * DV);
    pout[t] = a0;
    pout[t + 256] = a1;
}

// KZ: finalize. Grid B*16 = 256 blocks (bid = b*16 + q), 256 threads.
// Global m/Z from 32 chunk stats; alphas rows [q*256,+256); ctx cols [q*128,+128).
__global__ __launch_bounds__(256) void kz_final(const float* __restrict__ scores,
                                                const float* __restrict__ partial,
                                                const float* __restrict__ chunkm,
                                                const float* __restrict__ chunkz,
                                                float* __restrict__ ctx,
                                                float* __restrict__ alphas) {
    int bid = blockIdx.x;
    int b = bid >> 4;
    int q = bid & 15;
    int t = threadIdx.x;

    __shared__ float s_m[NCH];
    __shared__ float s_z[NCH];
    __shared__ float s_half[128];

    if (t < NCH) {
        s_m[t] = chunkm[b * NCH + t];
        s_z[t] = chunkz[b * NCH + t];
    }
    __syncthreads();

    // every thread computes m, Z redundantly from 32 pairs (LDS broadcast)
    float m = -INFINITY;
#pragma unroll
    for (int i = 0; i < NCH; ++i) m = fmaxf(m, s_m[i]);
    float Z = 0.f;
#pragma unroll
    for (int i = 0; i < NCH; ++i) {
        float mi = s_m[i];
        if (mi != -INFINITY) Z += s_z[i] * __expf(mi - m);
    }
    float inv = 1.0f / Z;

    // alphas rows [q*256, q*256+256)
    {
        float sc = scores[(size_t)b * SEQ + q * 256 + t];
        float e = (sc == -INFINITY) ? 0.f : __expf(sc - m);
        alphas[(size_t)b * SEQ + q * 256 + t] = e * inv;
    }

    // ctx cols [q*128, q*128+128): half 0 sums chunks 0..15, half 1 sums 16..31
    int col = q * 128 + (t & 127);
    int half = t >> 7;
    float sum = 0.f;
    const float* pbase = partial + (size_t)b * NCH * DV + col;
#pragma unroll 4
    for (int cc = half * 16; cc < half * 16 + 16; ++cc) {
        float mi = s_m[cc];
        if (mi != -INFINITY) {
            float g = __expf(mi - m);
            sum += g * pbase[(size_t)cc * DV];
        }
    }
    if (half == 1) s_half[t & 127] = sum;
    __syncthreads();
    if (half == 0)
        ctx[(size_t)b * DV + col] = (sum + s_half[t]) * inv;
}

// ---------- fallback path (tiny ws) ----------
__global__ __launch_bounds__(256) void k2_scores(const float* __restrict__ pk,
                                                 const float* __restrict__ qv,
                                                 const float* __restrict__ we,
                                                 const int* __restrict__ mask,
                                                 float* __restrict__ scores) {
    int wave = threadIdx.x >> 6;
    int lane = threadIdx.x & 63;
    int r = blockIdx.x * 4 + wave;
    int b = r >> 12;
    if (mask[r] == 0) { if (lane == 0) scores[r] = -INFINITY; return; }
    const float4* row = (const float4*)(pk + (size_t)r * HDIM);
    const float4* q4  = (const float4*)(qv + b * HDIM);
    const float4* we4 = (const float4*)we;
    float acc = 0.f;
#pragma unroll
    for (int k = 0; k < 4; ++k) {
        int idx = k * 64 + lane;
        float4 p = row[idx];
        float4 q = q4[idx];
        float4 w = we4[idx];
        acc += tanh_fast(p.x + q.x) * w.x;
        acc += tanh_fast(p.y + q.y) * w.y;
        acc += tanh_fast(p.z + q.z) * w.z;
        acc += tanh_fast(p.w + q.w) * w.w;
    }
#pragma unroll
    for (int off = 32; off; off >>= 1) acc += __shfl_down(acc, off, 64);
    if (lane == 0) scores[r] = acc;
}

__global__ __launch_bounds__(256) void k3_softmax(const float* __restrict__ scores,
                                                  float* __restrict__ alphas) {
    int b = blockIdx.x;
    int t = threadIdx.x;
    const float* sc = scores + b * SEQ;
    float loc[16];
    float m = -INFINITY;
#pragma unroll
    for (int i = 0; i < 16; ++i) { loc[i] = sc[t + i * 256]; m = fmaxf(m, loc[i]); }
#pragma unroll
    for (int off = 32; off; off >>= 1) m = fmaxf(m, __shfl_down(m, off, 64));
    __shared__ float redm[4];
    if ((t & 63) == 0) redm[t >> 6] = m;
    __syncthreads();
    m = fmaxf(fmaxf(redm[0], redm[1]), fmaxf(redm[2], redm[3]));
    float sum = 0.f;
#pragma unroll
    for (int i = 0; i < 16; ++i) {
        loc[i] = (loc[i] == -INFINITY) ? 0.f : __expf(loc[i] - m);
        sum += loc[i];
    }
#pragma unroll
    for (int off = 32; off; off >>= 1) sum += __shfl_down(sum, off, 64);
    __shared__ float reds[4];
    if ((t & 63) == 0) reds[t >> 6] = sum;
    __syncthreads();
    float inv = 1.0f / (reds[0] + reds[1] + reds[2] + reds[3]);
#pragma unroll
    for (int i = 0; i < 16; ++i) alphas[b * SEQ + t + i * 256] = loc[i] * inv;
}

__global__ __launch_bounds__(256) void k4_atomic(const float* __restrict__ value,
                                                 const float* __restrict__ alphas,
                                                 float* __restrict__ ctx) {
    int bid = blockIdx.x;
    int ch = bid & 31;
    int dt = (bid >> 5) & 1;
    int b  = bid >> 6;
    int t  = threadIdx.x;
    const float4* v4 = (const float4*)(value + (size_t)b * SEQ * DV + dt * 1024);
    const float* al = alphas + b * SEQ + ch * 128;
    float4 acc = make_float4(0.f, 0.f, 0.f, 0.f);
    for (int s = 0; s < 128; ++s) {
        float a = al[s];
        if (a != 0.f) {
            float4 v = v4[(size_t)(ch * 128 + s) * (DV / 4) + t];
            acc.x += a * v.x; acc.y += a * v.y; acc.z += a * v.z; acc.w += a * v.w;
        }
    }
    float* dst = ctx + (size_t)b * DV + dt * 1024 + t * 4;
    atomicAdd(dst + 0, acc.x);
    atomicAdd(dst + 1, acc.y);
    atomicAdd(dst + 2, acc.z);
    atomicAdd(dst + 3, acc.w);
}

extern "C" void kernel_launch(void* const* d_in, const int* in_sizes, int n_in,
                              void* d_out, int out_size, void* d_ws, size_t ws_size,
                              hipStream_t stream) {
    const float* query = (const float*)d_in[0];
    const float* pk    = (const float*)d_in[1];
    const float* value = (const float*)d_in[2];
    const float* Wq    = (const float*)d_in[3];
    const float* we    = (const float*)d_in[4];
    const int*   mask  = (const int*)d_in[5];

    float* out    = (float*)d_out;
    float* ctx    = out;                      // [B, 2H]
    float* alphas = out + BATCH * DV;         // [B, S]

    float* ws      = (float*)d_ws;
    float* qws     = ws;                                 // 16384 floats
    float* scores  = ws + BATCH * HDIM;                  // 65536 floats
    float* chunkm  = scores + BATCH * SEQ;               // 512 floats
    float* chunkz  = chunkm + BATCH * NCH;               // 512 floats
    float* partial = chunkz + BATCH * NCH;               // B*NCH*DV = 1M floats

    k1_q<<<HDIM / 4, 256, 0, stream>>>(query, Wq, qws);

    size_t need = (size_t)(BATCH * HDIM + BATCH * SEQ + 2 * BATCH * NCH
                           + (size_t)BATCH * NCH * DV) * sizeof(float);
    if (ws_size >= need) {
        kf_fused<<<BATCH * NCH, 256, 0, stream>>>(pk, qws, we, mask, value,
                                                  scores, partial, chunkm, chunkz);
        kz_final<<<BATCH * 16, 256, 0, stream>>>(scores, partial, chunkm, chunkz,
                                                 ctx, alphas);
    } else {
        k2_scores<<<(BATCH * SEQ) / 4, 256, 0, stream>>>(pk, qws, we, mask, scores);
        k3_softmax<<<BATCH, 256, 0, stream>>>(scores, alphas);
        (void)hipMemsetAsync(ctx, 0, (size_t)BATCH * DV * sizeof(float), stream);
        k4_atomic<<<BATCH * 64, 256, 0, stream>>>(value, alphas, ctx);
    }
}

// Round 7
// 91.600 us; speedup vs baseline: 1.2301x; 1.1994x over previous
//
#include <hip/hip_runtime.h>
#include <math.h>

#define BATCH 16
#define SEQ   4096
#define HDIM  1024
#define DV    2048          // 2*H
#define NCH   32            // s-chunks in fused kernel
#define SCH   (SEQ / NCH)   // 128 rows per chunk
#define KFT   512           // threads per kf block (8 waves)

typedef float vf4 __attribute__((ext_vector_type(4)));

__device__ __forceinline__ float tanh_fast(float x) {
    // tanh(x) = 1 - 2/(1+exp(2x)); robust at +/-inf
    float e = __expf(2.0f * x);
    return 1.0f - 2.0f * __builtin_amdgcn_rcpf(1.0f + e);
}

__device__ __forceinline__ float4 ntload4(const float4* p) {
    vf4 v = __builtin_nontemporal_load((const vf4*)p);
    return make_float4(v.x, v.y, v.z, v.w);
}

// K1: q[b,o] = sum_h query[b,h] * Wq[o,h]   (wave per o, loop over b)
__global__ __launch_bounds__(256) void k1_q(const float* __restrict__ query,
                                            const float* __restrict__ Wq,
                                            float* __restrict__ qout) {
    int wave = threadIdx.x >> 6;
    int lane = threadIdx.x & 63;
    int o = blockIdx.x * 4 + wave;
    const float4* wq4 = (const float4*)(Wq + (size_t)o * HDIM);
    float4 w[4];
#pragma unroll
    for (int k = 0; k < 4; ++k) w[k] = wq4[k * 64 + lane];
#pragma unroll
    for (int b = 0; b < BATCH; ++b) {
        const float4* q4 = (const float4*)(query + b * HDIM);
        float acc = 0.f;
#pragma unroll
        for (int k = 0; k < 4; ++k) {
            float4 q = q4[k * 64 + lane];
            acc += w[k].x * q.x + w[k].y * q.y + w[k].z * q.z + w[k].w * q.w;
        }
#pragma unroll
        for (int off = 32; off; off >>= 1) acc += __shfl_down(acc, off, 64);
        if (lane == 0) qout[b * HDIM + o] = acc;
    }
}

// KF: fused scores + chunk-local exp + context partials + chunk stats.
// Grid: B*NCH = 512 blocks (bid = b*NCH + c), 512 threads (8 waves).
// 2 blocks/CU -> 16 waves/CU; 512 DRAM stream fronts.
__global__ __launch_bounds__(KFT) void kf_fused(const float* __restrict__ pk,
                                                const float* __restrict__ qv,
                                                const float* __restrict__ we,
                                                const int* __restrict__ mask,
                                                const float* __restrict__ value,
                                                float* __restrict__ scores,
                                                float* __restrict__ partial,
                                                float* __restrict__ chunkm,
                                                float* __restrict__ chunkz) {
    int bid = blockIdx.x;
    int b = bid >> 5;                 // NCH = 32
    int c = bid & (NCH - 1);
    int s0 = c * SCH;
    int t = threadIdx.x;
    int wave = t >> 6;
    int lane = t & 63;

    __shared__ float s_sc[SCH];
    __shared__ float s_a[SCH];
    __shared__ int   s_list[SCH];
    __shared__ int   s_nact;
    __shared__ float redm[8];
    __shared__ float redz[8];

    // ---- compaction: wave 0 ballots the chunk's 128 rows in two halves ----
    if (t < 64) {
        int r0 = b * SEQ + s0 + t;
        int p0 = (mask[r0] != 0);
        unsigned long long b0 = __ballot(p0);
        int n0 = __popcll(b0);
        if (p0) {
            s_list[__popcll(b0 & ((1ull << lane) - 1ull))] = t;
        } else {
            s_sc[t] = -INFINITY;
            scores[r0] = -INFINITY;
        }
        int r1 = b * SEQ + s0 + 64 + t;
        int p1 = (mask[r1] != 0);
        unsigned long long b1 = __ballot(p1);
        if (p1) {
            s_list[n0 + __popcll(b1 & ((1ull << lane) - 1ull))] = 64 + t;
        } else {
            s_sc[64 + t] = -INFINITY;
            scores[r1] = -INFINITY;
        }
        if (lane == 0) s_nact = n0 + __popcll(b1);
    }

    const float4* q4  = (const float4*)(qv + b * HDIM);
    const float4* we4 = (const float4*)we;
    float4 qr[4], wr[4];
#pragma unroll
    for (int k = 0; k < 4; ++k) {
        qr[k] = q4[k * 64 + lane];
        wr[k] = we4[k * 64 + lane];
    }
    __syncthreads();
    int nact = s_nact;

    // ---- phase 1: scores for active rows only (wave-strided over 8 waves) ----
    for (int j = wave; j < nact; j += 8) {
        int s = s_list[j];
        int r = b * SEQ + s0 + s;
        const float4* row = (const float4*)(pk + (size_t)r * HDIM);
        float acc = 0.f;
#pragma unroll
        for (int k = 0; k < 4; ++k) {
            float4 p = ntload4(row + k * 64 + lane);
            acc += tanh_fast(p.x + qr[k].x) * wr[k].x;
            acc += tanh_fast(p.y + qr[k].y) * wr[k].y;
            acc += tanh_fast(p.z + qr[k].z) * wr[k].z;
            acc += tanh_fast(p.w + qr[k].w) * wr[k].w;
        }
#pragma unroll
        for (int off = 32; off; off >>= 1) acc += __shfl_down(acc, off, 64);
        if (lane == 0) {
            s_sc[s] = acc;
            scores[r] = acc;
        }
    }
    __syncthreads();

    // ---- chunk max over 128 values (waves 0,1 carry data) ----
    float mval = (t < SCH) ? s_sc[t] : -INFINITY;
    float mr = mval;
#pragma unroll
    for (int off = 32; off; off >>= 1) mr = fmaxf(mr, __shfl_down(mr, off, 64));
    if (lane == 0) redm[wave] = mr;
    __syncthreads();
    float mc = -INFINITY;
#pragma unroll
    for (int i = 0; i < 8; ++i) mc = fmaxf(mc, redm[i]);

    // weights a_s = exp(sc - m_c); z_c = sum a_s
    float av = 0.f;
    if (t < SCH) {
        av = (mval == -INFINITY || mc == -INFINITY) ? 0.f : __expf(mval - mc);
        s_a[t] = av;
    }
    float zr = av;
#pragma unroll
    for (int off = 32; off; off >>= 1) zr += __shfl_down(zr, off, 64);
    if (lane == 0) redz[wave] = zr;
    __syncthreads();
    if (t == 0) {
        float z = 0.f;
#pragma unroll
        for (int i = 0; i < 8; ++i) z += redz[i];
        chunkm[bid] = mc;
        chunkz[bid] = z;
    }

    // ---- phase 2: weighted value accumulation; thread t owns one float4 col ----
    const float4* v4 = (const float4*)(value + (size_t)b * SEQ * DV);
    float4 a0 = make_float4(0.f, 0.f, 0.f, 0.f);
    for (int j = 0; j < nact; ++j) {
        int s = s_list[j];
        float a = s_a[s];
        float4 u = ntload4(v4 + (size_t)(s0 + s) * (DV / 4) + t);
        a0.x += a * u.x; a0.y += a * u.y; a0.z += a * u.z; a0.w += a * u.w;
    }
    ((float4*)(partial + (size_t)bid * DV))[t] = a0;
}

// KZ: finalize. Grid B*16 = 256 blocks (bid = b*16 + q), 256 threads.
// Global m/Z from 32 chunk stats; alphas rows [q*256,+256); ctx cols [q*128,+128).
__global__ __launch_bounds__(256) void kz_final(const float* __restrict__ scores,
                                                const float* __restrict__ partial,
                                                const float* __restrict__ chunkm,
                                                const float* __restrict__ chunkz,
                                                float* __restrict__ ctx,
                                                float* __restrict__ alphas) {
    int bid = blockIdx.x;
    int b = bid >> 4;
    int q = bid & 15;
    int t = threadIdx.x;

    __shared__ float s_m[NCH];
    __shared__ float s_z[NCH];
    __shared__ float s_half[128];

    if (t < NCH) {
        s_m[t] = chunkm[b * NCH + t];
        s_z[t] = chunkz[b * NCH + t];
    }
    __syncthreads();

    float m = -INFINITY;
#pragma unroll
    for (int i = 0; i < NCH; ++i) m = fmaxf(m, s_m[i]);
    float Z = 0.f;
#pragma unroll
    for (int i = 0; i < NCH; ++i) {
        float mi = s_m[i];
        if (mi != -INFINITY) Z += s_z[i] * __expf(mi - m);
    }
    float inv = 1.0f / Z;

    // alphas rows [q*256, q*256+256)
    {
        float sc = scores[(size_t)b * SEQ + q * 256 + t];
        float e = (sc == -INFINITY) ? 0.f : __expf(sc - m);
        alphas[(size_t)b * SEQ + q * 256 + t] = e * inv;
    }

    // ctx cols [q*128, q*128+128): half 0 sums chunks 0..15, half 1 sums 16..31
    int col = q * 128 + (t & 127);
    int half = t >> 7;
    float sum = 0.f;
    const float* pbase = partial + (size_t)b * NCH * DV + col;
#pragma unroll 4
    for (int cc = half * 16; cc < half * 16 + 16; ++cc) {
        float mi = s_m[cc];
        if (mi != -INFINITY) {
            float g = __expf(mi - m);
            sum += g * pbase[(size_t)cc * DV];
        }
    }
    if (half == 1) s_half[t & 127] = sum;
    __syncthreads();
    if (half == 0)
        ctx[(size_t)b * DV + col] = (sum + s_half[t]) * inv;
}

// ---------- fallback path (tiny ws) ----------
__global__ __launch_bounds__(256) void k2_scores(const float* __restrict__ pk,
                                                 const float* __restrict__ qv,
                                                 const float* __restrict__ we,
                                                 const int* __restrict__ mask,
                                                 float* __restrict__ scores) {
    int wave = threadIdx.x >> 6;
    int lane = threadIdx.x & 63;
    int r = blockIdx.x * 4 + wave;
    int b = r >> 12;
    if (mask[r] == 0) { if (lane == 0) scores[r] = -INFINITY; return; }
    const float4* row = (const float4*)(pk + (size_t)r * HDIM);
    const float4* q4  = (const float4*)(qv + b * HDIM);
    const float4* we4 = (const float4*)we;
    float acc = 0.f;
#pragma unroll
    for (int k = 0; k < 4; ++k) {
        int idx = k * 64 + lane;
        float4 p = row[idx];
        float4 q = q4[idx];
        float4 w = we4[idx];
        acc += tanh_fast(p.x + q.x) * w.x;
        acc += tanh_fast(p.y + q.y) * w.y;
        acc += tanh_fast(p.z + q.z) * w.z;
        acc += tanh_fast(p.w + q.w) * w.w;
    }
#pragma unroll
    for (int off = 32; off; off >>= 1) acc += __shfl_down(acc, off, 64);
    if (lane == 0) scores[r] = acc;
}

__global__ __launch_bounds__(256) void k3_softmax(const float* __restrict__ scores,
                                                  float* __restrict__ alphas) {
    int b = blockIdx.x;
    int t = threadIdx.x;
    const float* sc = scores + b * SEQ;
    float loc[16];
    float m = -INFINITY;
#pragma unroll
    for (int i = 0; i < 16; ++i) { loc[i] = sc[t + i * 256]; m = fmaxf(m, loc[i]); }
#pragma unroll
    for (int off = 32; off; off >>= 1) m = fmaxf(m, __shfl_down(m, off, 64));
    __shared__ float redm[4];
    if ((t & 63) == 0) redm[t >> 6] = m;
    __syncthreads();
    m = fmaxf(fmaxf(redm[0], redm[1]), fmaxf(redm[2], redm[3]));
    float sum = 0.f;
#pragma unroll
    for (int i = 0; i < 16; ++i) {
        loc[i] = (loc[i] == -INFINITY) ? 0.f : __expf(loc[i] - m);
        sum += loc[i];
    }
#pragma unroll
    for (int off = 32; off; off >>= 1) sum += __shfl_down(sum, off, 64);
    __shared__ float reds[4];
    if ((t & 63) == 0) reds[t >> 6] = sum;
    __syncthreads();
    float inv = 1.0f / (reds[0] + reds[1] + reds[2] + reds[3]);
#pragma unroll
    for (int i = 0; i < 16; ++i) alphas[b * SEQ + t + i * 256] = loc[i] * inv;
}

__global__ __launch_bounds__(256) void k4_atomic(const float* __restrict__ value,
                                                 const float* __restrict__ alphas,
                                                 float* __restrict__ ctx) {
    int bid = blockIdx.x;
    int ch = bid & 31;
    int dt = (bid >> 5) & 1;
    int b  = bid >> 6;
    int t  = threadIdx.x;
    const float4* v4 = (const float4*)(value + (size_t)b * SEQ * DV + dt * 1024);
    const float* al = alphas + b * SEQ + ch * 128;
    float4 acc = make_float4(0.f, 0.f, 0.f, 0.f);
    for (int s = 0; s < 128; ++s) {
        float a = al[s];
        if (a != 0.f) {
            float4 v = v4[(size_t)(ch * 128 + s) * (DV / 4) + t];
            acc.x += a * v.x; acc.y += a * v.y; acc.z += a * v.z; acc.w += a * v.w;
        }
    }
    float* dst = ctx + (size_t)b * DV + dt * 1024 + t * 4;
    atomicAdd(dst + 0, acc.x);
    atomicAdd(dst + 1, acc.y);
    atomicAdd(dst + 2, acc.z);
    atomicAdd(dst + 3, acc.w);
}

extern "C" void kernel_launch(void* const* d_in, const int* in_sizes, int n_in,
                              void* d_out, int out_size, void* d_ws, size_t ws_size,
                              hipStream_t stream) {
    const float* query = (const float*)d_in[0];
    const float* pk    = (const float*)d_in[1];
    const float* value = (const float*)d_in[2];
    const float* Wq    = (const float*)d_in[3];
    const float* we    = (const float*)d_in[4];
    const int*   mask  = (const int*)d_in[5];

    float* out    = (float*)d_out;
    float* ctx    = out;                      // [B, 2H]
    float* alphas = out + BATCH * DV;         // [B, S]

    float* ws      = (float*)d_ws;
    float* qws     = ws;                                 // 16384 floats
    float* scores  = ws + BATCH * HDIM;                  // 65536 floats
    float* chunkm  = scores + BATCH * SEQ;               // 512 floats
    float* chunkz  = chunkm + BATCH * NCH;               // 512 floats
    float* partial = chunkz + BATCH * NCH;               // B*NCH*DV = 1M floats

    k1_q<<<HDIM / 4, 256, 0, stream>>>(query, Wq, qws);

    size_t need = (size_t)(BATCH * HDIM + BATCH * SEQ + 2 * BATCH * NCH
                           + (size_t)BATCH * NCH * DV) * sizeof(float);
    if (ws_size >= need) {
        kf_fused<<<BATCH * NCH, KFT, 0, stream>>>(pk, qws, we, mask, value,
                                                  scores, partial, chunkm, chunkz);
        kz_final<<<BATCH * 16, 256, 0, stream>>>(scores, partial, chunkm, chunkz,
                                                 ctx, alphas);
    } else {
        k2_scores<<<(BATCH * SEQ) / 4, 256, 0, stream>>>(pk, qws, we, mask, scores);
        k3_softmax<<<BATCH, 256, 0, stream>>>(scores, alphas);
        (void)hipMemsetAsync(ctx, 0, (size_t)BATCH * DV * sizeof(float), stream);
        k4_atomic<<<BATCH * 64, 256, 0, stream>>>(value, alphas, ctx);
    }
}

// Round 8
// 90.777 us; speedup vs baseline: 1.2413x; 1.0091x over previous
//
#include <hip/hip_runtime.h>
#include <math.h>

#define BATCH 16
#define SEQ   4096
#define HDIM  1024
#define DV    2048          // 2*H
#define NCH   32            // s-chunks in fused kernel
#define SCH   (SEQ / NCH)   // 128 rows per chunk
#define KFT   512           // threads per kf block (8 waves)

typedef float vf4 __attribute__((ext_vector_type(4)));

__device__ __forceinline__ float tanh_fast(float x) {
    // tanh(x) = 1 - 2/(1+exp(2x)); robust at +/-inf
    float e = __expf(2.0f * x);
    return 1.0f - 2.0f * __builtin_amdgcn_rcpf(1.0f + e);
}

__device__ __forceinline__ float4 ntload4(const float4* p) {
    vf4 v = __builtin_nontemporal_load((const vf4*)p);
    return make_float4(v.x, v.y, v.z, v.w);
}

// K1: q[b,o] = sum_h query[b,h] * Wq[o,h]   (wave per o, loop over b)
__global__ __launch_bounds__(256) void k1_q(const float* __restrict__ query,
                                            const float* __restrict__ Wq,
                                            float* __restrict__ qout) {
    int wave = threadIdx.x >> 6;
    int lane = threadIdx.x & 63;
    int o = blockIdx.x * 4 + wave;
    const float4* wq4 = (const float4*)(Wq + (size_t)o * HDIM);
    float4 w[4];
#pragma unroll
    for (int k = 0; k < 4; ++k) w[k] = wq4[k * 64 + lane];
#pragma unroll
    for (int b = 0; b < BATCH; ++b) {
        const float4* q4 = (const float4*)(query + b * HDIM);
        float acc = 0.f;
#pragma unroll
        for (int k = 0; k < 4; ++k) {
            float4 q = q4[k * 64 + lane];
            acc += w[k].x * q.x + w[k].y * q.y + w[k].z * q.z + w[k].w * q.w;
        }
#pragma unroll
        for (int off = 32; off; off >>= 1) acc += __shfl_down(acc, off, 64);
        if (lane == 0) qout[b * HDIM + o] = acc;
    }
}

// KF: fused scores + chunk-local exp + context partials + chunk stats.
// Grid: B*NCH = 512 blocks (bid = b*NCH + c), 512 threads (8 waves).
__global__ __launch_bounds__(KFT) void kf_fused(const float* __restrict__ pk,
                                                const float* __restrict__ qv,
                                                const float* __restrict__ we,
                                                const int* __restrict__ mask,
                                                const float* __restrict__ value,
                                                float* __restrict__ scores,
                                                float* __restrict__ partial,
                                                float* __restrict__ chunkm,
                                                float* __restrict__ chunkz) {
    int bid = blockIdx.x;
    int b = bid >> 5;                 // NCH = 32
    int c = bid & (NCH - 1);
    int s0 = c * SCH;
    int t = threadIdx.x;
    int wave = t >> 6;
    int lane = t & 63;

    __shared__ float s_sc[SCH];
    __shared__ float s_a[SCH];
    __shared__ int   s_list[SCH];
    __shared__ float s_aa[SCH];       // weights in compacted order
    __shared__ int   s_off[SCH];      // row offsets (float4 units) in compacted order
    __shared__ int   s_nact;
    __shared__ float redm[8];
    __shared__ float redz[8];

    // ---- compaction: wave 0 ballots the chunk's 128 rows in two halves ----
    if (t < 64) {
        int r0 = b * SEQ + s0 + t;
        int p0 = (mask[r0] != 0);
        unsigned long long b0 = __ballot(p0);
        int n0 = __popcll(b0);
        if (p0) {
            s_list[__popcll(b0 & ((1ull << lane) - 1ull))] = t;
        } else {
            s_sc[t] = -INFINITY;
            scores[r0] = -INFINITY;
        }
        int r1 = b * SEQ + s0 + 64 + t;
        int p1 = (mask[r1] != 0);
        unsigned long long b1 = __ballot(p1);
        if (p1) {
            s_list[n0 + __popcll(b1 & ((1ull << lane) - 1ull))] = 64 + t;
        } else {
            s_sc[64 + t] = -INFINITY;
            scores[r1] = -INFINITY;
        }
        if (lane == 0) s_nact = n0 + __popcll(b1);
    }

    const float4* q4  = (const float4*)(qv + b * HDIM);
    const float4* we4 = (const float4*)we;
    float4 qr[4], wr[4];
#pragma unroll
    for (int k = 0; k < 4; ++k) {
        qr[k] = q4[k * 64 + lane];
        wr[k] = we4[k * 64 + lane];
    }
    __syncthreads();
    int nact = s_nact;

    // ---- phase 1: scores for active rows only (wave-strided over 8 waves) ----
    for (int j = wave; j < nact; j += 8) {
        int s = s_list[j];
        int r = b * SEQ + s0 + s;
        const float4* row = (const float4*)(pk + (size_t)r * HDIM);
        float acc = 0.f;
#pragma unroll
        for (int k = 0; k < 4; ++k) {
            float4 p = ntload4(row + k * 64 + lane);
            acc += tanh_fast(p.x + qr[k].x) * wr[k].x;
            acc += tanh_fast(p.y + qr[k].y) * wr[k].y;
            acc += tanh_fast(p.z + qr[k].z) * wr[k].z;
            acc += tanh_fast(p.w + qr[k].w) * wr[k].w;
        }
#pragma unroll
        for (int off = 32; off; off >>= 1) acc += __shfl_down(acc, off, 64);
        if (lane == 0) {
            s_sc[s] = acc;
            scores[r] = acc;
        }
    }
    __syncthreads();

    // ---- chunk max over 128 values (waves 0,1 carry data) ----
    float mval = (t < SCH) ? s_sc[t] : -INFINITY;
    float mr = mval;
#pragma unroll
    for (int off = 32; off; off >>= 1) mr = fmaxf(mr, __shfl_down(mr, off, 64));
    if (lane == 0) redm[wave] = mr;
    __syncthreads();
    float mc = -INFINITY;
#pragma unroll
    for (int i = 0; i < 8; ++i) mc = fmaxf(mc, redm[i]);

    // weights a_s = exp(sc - m_c); z_c = sum a_s
    float av = 0.f;
    if (t < SCH) {
        av = (mval == -INFINITY || mc == -INFINITY) ? 0.f : __expf(mval - mc);
        s_a[t] = av;
    }
    float zr = av;
#pragma unroll
    for (int off = 32; off; off >>= 1) zr += __shfl_down(zr, off, 64);
    if (lane == 0) redz[wave] = zr;
    __syncthreads();
    if (t == 0) {
        float z = 0.f;
#pragma unroll
        for (int i = 0; i < 8; ++i) z += redz[i];
        chunkm[bid] = mc;
        chunkz[bid] = z;
    }
    // compacted weights + row offsets (needs s_a complete -> after the barrier above)
    if (t < SCH && t < nact) {
        int s = s_list[t];
        s_aa[t]  = s_a[s];
        s_off[t] = (s0 + s) * (DV / 4);
    }
    __syncthreads();

    // ---- phase 2: weighted value accumulation, 4-row unroll, 4 accumulators ----
    const float4* v4 = (const float4*)(value + (size_t)b * SEQ * DV);
    float4 acc0 = make_float4(0.f, 0.f, 0.f, 0.f);
    float4 acc1 = make_float4(0.f, 0.f, 0.f, 0.f);
    float4 acc2 = make_float4(0.f, 0.f, 0.f, 0.f);
    float4 acc3 = make_float4(0.f, 0.f, 0.f, 0.f);
    int j = 0;
    for (; j + 3 < nact; j += 4) {
        int   o0 = s_off[j],     o1 = s_off[j + 1];
        int   o2 = s_off[j + 2], o3 = s_off[j + 3];
        float w0 = s_aa[j],      w1 = s_aa[j + 1];
        float w2 = s_aa[j + 2],  w3 = s_aa[j + 3];
        float4 u0 = ntload4(v4 + o0 + t);
        float4 u1 = ntload4(v4 + o1 + t);
        float4 u2 = ntload4(v4 + o2 + t);
        float4 u3 = ntload4(v4 + o3 + t);
        acc0.x += w0 * u0.x; acc0.y += w0 * u0.y; acc0.z += w0 * u0.z; acc0.w += w0 * u0.w;
        acc1.x += w1 * u1.x; acc1.y += w1 * u1.y; acc1.z += w1 * u1.z; acc1.w += w1 * u1.w;
        acc2.x += w2 * u2.x; acc2.y += w2 * u2.y; acc2.z += w2 * u2.z; acc2.w += w2 * u2.w;
        acc3.x += w3 * u3.x; acc3.y += w3 * u3.y; acc3.z += w3 * u3.z; acc3.w += w3 * u3.w;
    }
    for (; j < nact; ++j) {
        int   o = s_off[j];
        float w = s_aa[j];
        float4 u = ntload4(v4 + o + t);
        acc0.x += w * u.x; acc0.y += w * u.y; acc0.z += w * u.z; acc0.w += w * u.w;
    }
    acc0.x += acc1.x + acc2.x + acc3.x;
    acc0.y += acc1.y + acc2.y + acc3.y;
    acc0.z += acc1.z + acc2.z + acc3.z;
    acc0.w += acc1.w + acc2.w + acc3.w;
    ((float4*)(partial + (size_t)bid * DV))[t] = acc0;
}

// KZ: finalize. Grid B*16 = 256 blocks (bid = b*16 + q), 256 threads.
__global__ __launch_bounds__(256) void kz_final(const float* __restrict__ scores,
                                                const float* __restrict__ partial,
                                                const float* __restrict__ chunkm,
                                                const float* __restrict__ chunkz,
                                                float* __restrict__ ctx,
                                                float* __restrict__ alphas) {
    int bid = blockIdx.x;
    int b = bid >> 4;
    int q = bid & 15;
    int t = threadIdx.x;

    __shared__ float s_m[NCH];
    __shared__ float s_z[NCH];
    __shared__ float s_half[128];

    if (t < NCH) {
        s_m[t] = chunkm[b * NCH + t];
        s_z[t] = chunkz[b * NCH + t];
    }
    __syncthreads();

    float m = -INFINITY;
#pragma unroll
    for (int i = 0; i < NCH; ++i) m = fmaxf(m, s_m[i]);
    float Z = 0.f;
#pragma unroll
    for (int i = 0; i < NCH; ++i) {
        float mi = s_m[i];
        if (mi != -INFINITY) Z += s_z[i] * __expf(mi - m);
    }
    float inv = 1.0f / Z;

    // alphas rows [q*256, q*256+256)
    {
        float sc = scores[(size_t)b * SEQ + q * 256 + t];
        float e = (sc == -INFINITY) ? 0.f : __expf(sc - m);
        alphas[(size_t)b * SEQ + q * 256 + t] = e * inv;
    }

    // ctx cols [q*128, q*128+128): half 0 sums chunks 0..15, half 1 sums 16..31
    int col = q * 128 + (t & 127);
    int half = t >> 7;
    float sum = 0.f;
    const float* pbase = partial + (size_t)b * NCH * DV + col;
#pragma unroll 4
    for (int cc = half * 16; cc < half * 16 + 16; ++cc) {
        float mi = s_m[cc];
        if (mi != -INFINITY) {
            float g = __expf(mi - m);
            sum += g * pbase[(size_t)cc * DV];
        }
    }
    if (half == 1) s_half[t & 127] = sum;
    __syncthreads();
    if (half == 0)
        ctx[(size_t)b * DV + col] = (sum + s_half[t]) * inv;
}

// ---------- fallback path (tiny ws) ----------
__global__ __launch_bounds__(256) void k2_scores(const float* __restrict__ pk,
                                                 const float* __restrict__ qv,
                                                 const float* __restrict__ we,
                                                 const int* __restrict__ mask,
                                                 float* __restrict__ scores) {
    int wave = threadIdx.x >> 6;
    int lane = threadIdx.x & 63;
    int r = blockIdx.x * 4 + wave;
    int b = r >> 12;
    if (mask[r] == 0) { if (lane == 0) scores[r] = -INFINITY; return; }
    const float4* row = (const float4*)(pk + (size_t)r * HDIM);
    const float4* q4  = (const float4*)(qv + b * HDIM);
    const float4* we4 = (const float4*)we;
    float acc = 0.f;
#pragma unroll
    for (int k = 0; k < 4; ++k) {
        int idx = k * 64 + lane;
        float4 p = row[idx];
        float4 q = q4[idx];
        float4 w = we4[idx];
        acc += tanh_fast(p.x + q.x) * w.x;
        acc += tanh_fast(p.y + q.y) * w.y;
        acc += tanh_fast(p.z + q.z) * w.z;
        acc += tanh_fast(p.w + q.w) * w.w;
    }
#pragma unroll
    for (int off = 32; off; off >>= 1) acc += __shfl_down(acc, off, 64);
    if (lane == 0) scores[r] = acc;
}

__global__ __launch_bounds__(256) void k3_softmax(const float* __restrict__ scores,
                                                  float* __restrict__ alphas) {
    int b = blockIdx.x;
    int t = threadIdx.x;
    const float* sc = scores + b * SEQ;
    float loc[16];
    float m = -INFINITY;
#pragma unroll
    for (int i = 0; i < 16; ++i) { loc[i] = sc[t + i * 256]; m = fmaxf(m, loc[i]); }
#pragma unroll
    for (int off = 32; off; off >>= 1) m = fmaxf(m, __shfl_down(m, off, 64));
    __shared__ float redm[4];
    if ((t & 63) == 0) redm[t >> 6] = m;
    __syncthreads();
    m = fmaxf(fmaxf(redm[0], redm[1]), fmaxf(redm[2], redm[3]));
    float sum = 0.f;
#pragma unroll
    for (int i = 0; i < 16; ++i) {
        loc[i] = (loc[i] == -INFINITY) ? 0.f : __expf(loc[i] - m);
        sum += loc[i];
    }
#pragma unroll
    for (int off = 32; off; off >>= 1) sum += __shfl_down(sum, off, 64);
    __shared__ float reds[4];
    if ((t & 63) == 0) reds[t >> 6] = sum;
    __syncthreads();
    float inv = 1.0f / (reds[0] + reds[1] + reds[2] + reds[3]);
#pragma unroll
    for (int i = 0; i < 16; ++i) alphas[b * SEQ + t + i * 256] = loc[i] * inv;
}

__global__ __launch_bounds__(256) void k4_atomic(const float* __restrict__ value,
                                                 const float* __restrict__ alphas,
                                                 float* __restrict__ ctx) {
    int bid = blockIdx.x;
    int ch = bid & 31;
    int dt = (bid >> 5) & 1;
    int b  = bid >> 6;
    int t  = threadIdx.x;
    const float4* v4 = (const float4*)(value + (size_t)b * SEQ * DV + dt * 1024);
    const float* al = alphas + b * SEQ + ch * 128;
    float4 acc = make_float4(0.f, 0.f, 0.f, 0.f);
    for (int s = 0; s < 128; ++s) {
        float a = al[s];
        if (a != 0.f) {
            float4 v = v4[(size_t)(ch * 128 + s) * (DV / 4) + t];
            acc.x += a * v.x; acc.y += a * v.y; acc.z += a * v.z; acc.w += a * v.w;
        }
    }
    float* dst = ctx + (size_t)b * DV + dt * 1024 + t * 4;
    atomicAdd(dst + 0, acc.x);
    atomicAdd(dst + 1, acc.y);
    atomicAdd(dst + 2, acc.z);
    atomicAdd(dst + 3, acc.w);
}

extern "C" void kernel_launch(void* const* d_in, const int* in_sizes, int n_in,
                              void* d_out, int out_size, void* d_ws, size_t ws_size,
                              hipStream_t stream) {
    const float* query = (const float*)d_in[0];
    const float* pk    = (const float*)d_in[1];
    const float* value = (const float*)d_in[2];
    const float* Wq    = (const float*)d_in[3];
    const float* we    = (const float*)d_in[4];
    const int*   mask  = (const int*)d_in[5];

    float* out    = (float*)d_out;
    float* ctx    = out;                      // [B, 2H]
    float* alphas = out + BATCH * DV;         // [B, S]

    float* ws      = (float*)d_ws;
    float* qws     = ws;                                 // 16384 floats
    float* scores  = ws + BATCH * HDIM;                  // 65536 floats
    float* chunkm  = scores + BATCH * SEQ;               // 512 floats
    float* chunkz  = chunkm + BATCH * NCH;               // 512 floats
    float* partial = chunkz + BATCH * NCH;               // B*NCH*DV = 1M floats

    k1_q<<<HDIM / 4, 256, 0, stream>>>(query, Wq, qws);

    size_t need = (size_t)(BATCH * HDIM + BATCH * SEQ + 2 * BATCH * NCH
                           + (size_t)BATCH * NCH * DV) * sizeof(float);
    if (ws_size >= need) {
        kf_fused<<<BATCH * NCH, KFT, 0, stream>>>(pk, qws, we, mask, value,
                                                  scores, partial, chunkm, chunkz);
        kz_final<<<BATCH * 16, 256, 0, stream>>>(scores, partial, chunkm, chunkz,
                                                 ctx, alphas);
    } else {
        k2_scores<<<(BATCH * SEQ) / 4, 256, 0, stream>>>(pk, qws, we, mask, scores);
        k3_softmax<<<BATCH, 256, 0, stream>>>(scores, alphas);
        (void)hipMemsetAsync(ctx, 0, (size_t)BATCH * DV * sizeof(float), stream);
        k4_atomic<<<BATCH * 64, 256, 0, stream>>>(value, alphas, ctx);
    }
}